// Round 2
// baseline (209.068 us; speedup 1.0000x reference)
//
#include <hip/hip_runtime.h>

#define BINS 10
#define ALPHA 0.75f

constexpr int NB = 2048;   // pass-1 blocks (memory-bound cap, grid-stride)
constexpr int NT = 256;    // threads per block (4 waves)

// Pass 1: fused elementwise + per-bin {count, loss-sum} accumulation.
// Each thread keeps 10 private (count, loss_sum) register pairs (static
// indexing only — unrolled compare per bin), grid-strides over float4/int4
// vectors, then wave-shuffle + LDS reduce to ONE deterministic partial
// per block (no atomics).
__global__ __launch_bounds__(NT) void ghm_pass1(
    const float* __restrict__ o1f, const float* __restrict__ o2f,
    const int* __restrict__ tgt, float* __restrict__ lsum_part,
    unsigned int* __restrict__ cnt_part, int n)
{
  const float4* o1 = reinterpret_cast<const float4*>(o1f);
  const float4* o2 = reinterpret_cast<const float4*>(o2f);
  const int4*   tg = reinterpret_cast<const int4*>(tgt);
  const int n4 = n >> 2;

  float ls[BINS];
  unsigned int c[BINS];
#pragma unroll
  for (int b = 0; b < BINS; ++b) { ls[b] = 0.0f; c[b] = 0u; }

  const int tid = blockIdx.x * NT + threadIdx.x;
  const int stride = gridDim.x * NT;

  // loss = max(0, -t*diff); g = sigmoid(-diff*(2t-1)) = 1/(1+exp(diff*(2t-1)))
#define GHM_PROC(AX, BX, TX) do {                                   \
    float diff = (AX) - (BX);                                       \
    float tf   = (float)(TX);                                       \
    float sarg = diff * (2.0f * tf - 1.0f);                         \
    float e    = __expf(sarg);                                      \
    float g    = 1.0f / (1.0f + e);                                 \
    float loss = fmaxf(-tf * diff, 0.0f);                           \
    int bin    = (int)(g * 10.0f);                                  \
    bin = bin > (BINS - 1) ? (BINS - 1) : bin;                      \
    _Pragma("unroll")                                               \
    for (int b = 0; b < BINS; ++b) {                                \
      bool m = (bin == b);                                          \
      c[b]  += (unsigned int)m;                                     \
      ls[b] += m ? loss : 0.0f;                                     \
    }                                                               \
  } while (0)

  for (int i = tid; i < n4; i += stride) {
    float4 a  = o1[i];
    float4 bb = o2[i];
    int4   t  = tg[i];
    GHM_PROC(a.x, bb.x, t.x);
    GHM_PROC(a.y, bb.y, t.y);
    GHM_PROC(a.z, bb.z, t.z);
    GHM_PROC(a.w, bb.w, t.w);
  }
  // scalar tail (dead for N = 2^24, kept for generality)
  if (tid == 0) {
    for (int i = n4 * 4; i < n; ++i) GHM_PROC(o1f[i], o2f[i], tgt[i]);
  }
#undef GHM_PROC

  // wave64 shuffle reduce, then cross-wave via LDS
  const int lane = threadIdx.x & 63;
  const int wv   = threadIdx.x >> 6;
  __shared__ float        s_ls[NT / 64][BINS];
  __shared__ unsigned int s_c [NT / 64][BINS];
#pragma unroll
  for (int b = 0; b < BINS; ++b) {
    float v = ls[b];
    unsigned int cv = c[b];
#pragma unroll
    for (int off = 32; off >= 1; off >>= 1) {
      v  += __shfl_down(v, off, 64);
      cv += __shfl_down(cv, off, 64);
    }
    if (lane == 0) { s_ls[wv][b] = v; s_c[wv][b] = cv; }
  }
  __syncthreads();
  if (threadIdx.x < BINS) {
    float v = 0.0f; unsigned int cv = 0u;
#pragma unroll
    for (int w = 0; w < NT / 64; ++w) { v += s_ls[w][threadIdx.x]; cv += s_c[w][threadIdx.x]; }
    lsum_part[blockIdx.x * BINS + threadIdx.x] = v;
    cnt_part [blockIdx.x * BINS + threadIdx.x] = cv;
  }
}

// Pass 2: one block reduces the per-block partials in double, applies the
// per-bin weight w[b] = max((float)count, 1)^-0.75 (matching reference's
// f32 cast of counts), writes the scalar mean.
__global__ __launch_bounds__(NT) void ghm_pass2(
    const float* __restrict__ lsum_part, const unsigned int* __restrict__ cnt_part,
    float* __restrict__ out, int nparts, int n)
{
  double ls[BINS];
  unsigned long long c[BINS];
#pragma unroll
  for (int b = 0; b < BINS; ++b) { ls[b] = 0.0; c[b] = 0ull; }

  for (int i = threadIdx.x; i < nparts; i += NT) {
#pragma unroll
    for (int b = 0; b < BINS; ++b) {
      ls[b] += (double)lsum_part[i * BINS + b];
      c[b]  += (unsigned long long)cnt_part[i * BINS + b];
    }
  }

  const int lane = threadIdx.x & 63;
  const int wv   = threadIdx.x >> 6;
  __shared__ double             s_ls[NT / 64][BINS];
  __shared__ unsigned long long s_c [NT / 64][BINS];
#pragma unroll
  for (int b = 0; b < BINS; ++b) {
    double v = ls[b];
    unsigned long long cv = c[b];
#pragma unroll
    for (int off = 32; off >= 1; off >>= 1) {
      v  += __shfl_down(v, off, 64);
      cv += __shfl_down(cv, off, 64);
    }
    if (lane == 0) { s_ls[wv][b] = v; s_c[wv][b] = cv; }
  }
  __syncthreads();
  if (threadIdx.x == 0) {
    double total = 0.0;
#pragma unroll
    for (int b = 0; b < BINS; ++b) {
      double lv = 0.0;
      unsigned long long cv = 0ull;
#pragma unroll
      for (int w = 0; w < NT / 64; ++w) { lv += s_ls[w][b]; cv += s_c[w][b]; }
      float cf  = (float)cv;           // counts.astype(float32)
      float tot = fmaxf(cf, 1.0f);     // clip(counts, 1.0)
      float wgt = powf(tot, -ALPHA);   // tot ** -0.75
      total += lv * (double)wgt;
    }
    out[0] = (float)(total / (double)n);
  }
}

extern "C" void kernel_launch(void* const* d_in, const int* in_sizes, int n_in,
                              void* d_out, int out_size, void* d_ws, size_t ws_size,
                              hipStream_t stream) {
  const float* o1  = (const float*)d_in[0];
  const float* o2  = (const float*)d_in[1];
  const int*   tgt = (const int*)d_in[2];
  float* out = (float*)d_out;
  const int n = in_sizes[0];

  // ws layout: [NB][BINS] f32 loss partials, then [NB][BINS] u32 count partials
  int nb = NB;
  size_t need = (size_t)nb * BINS * (sizeof(float) + sizeof(unsigned int));
  while (nb > 1 && need > ws_size) { nb >>= 1; need >>= 1; }  // safety only
  float* lsum_part = (float*)d_ws;
  unsigned int* cnt_part = (unsigned int*)((char*)d_ws + (size_t)nb * BINS * sizeof(float));

  ghm_pass1<<<nb, NT, 0, stream>>>(o1, o2, tgt, lsum_part, cnt_part, n);
  ghm_pass2<<<1, NT, 0, stream>>>(lsum_part, cnt_part, out, nb, n);
}